// Round 11
// baseline (795.179 us; speedup 1.0000x reference)
//
#include <hip/hip_runtime.h>
#include <hip/hip_fp16.h>

constexpr int kNodes = 50000;
constexpr int kNE    = 800000;            // edges before self loops
constexpr int kFin   = 256;
constexpr int kC     = 32;
constexpr int kH     = 4;
constexpr int kHC    = 128;               // kH * kC
constexpr float kEps   = 1e-5f;
constexpr float kSlope = 0.2f;
constexpr float kShift = 8.0f;            // softmax-invariant global shift

// ---- zero-fill
__global__ void __launch_bounds__(256) k_fill0(unsigned* __restrict__ p, int n) {
    int i = blockIdx.x * 256 + threadIdx.x;
    if (i < n) p[i] = 0u;
}

// ---- K1: h0 = relu(node_ln(x @ W_emb + b_emb)); jk = h0.
// 8 nodes/block; x staged in LDS (8 KB); W read directly (32 KB, L1/L2-hot).
__global__ void __launch_bounds__(256) k_embed(
    const float* __restrict__ x, const float* __restrict__ W, const float* __restrict__ b,
    const float* __restrict__ lnw, const float* __restrict__ lnb,
    float* __restrict__ h, float* __restrict__ jk) {
    __shared__ float sx[8 * kFin];
    __shared__ float sy[8][33];
    int t = threadIdx.x;
    long base = (long)blockIdx.x * 8 * kFin;
    for (int r = 0; r < 8; ++r) sx[r * 256 + t] = x[base + r * 256 + t];
    __syncthreads();
    int ng = t >> 5, c = t & 31;
    const float* xp = sx + ng * kFin;
    float a0 = 0.f, a1 = 0.f, a2 = 0.f, a3 = 0.f;
    #pragma unroll 4
    for (int k = 0; k < kFin; k += 4) {
        a0 += xp[k]     * W[(k)     * kC + c];
        a1 += xp[k + 1] * W[(k + 1) * kC + c];
        a2 += xp[k + 2] * W[(k + 2) * kC + c];
        a3 += xp[k + 3] * W[(k + 3) * kC + c];
    }
    float y = (a0 + a1) + (a2 + a3) + b[c];
    sy[ng][c] = y;
    __syncthreads();
    float m = 0.f;
    for (int j = 0; j < kC; ++j) m += sy[ng][j];
    m *= (1.f / kC);
    float q = 0.f;
    for (int j = 0; j < kC; ++j) { float d = sy[ng][j] - m; q += d * d; }
    q *= (1.f / kC);
    float out = (y - m) * rsqrtf(q + kEps) * lnw[c] + lnb[c];
    out = fmaxf(out, 0.f);
    int node = blockIdx.x * 8 + ng;
    h[node * kC + c] = out;
    jk[node * kC + c] = out;
}

// ---- K2: xl = h@Wl + bl (fp16, HEAD-MAJOR [h][node][32]) ; xr = h@Wr + br (fp32).
__global__ void __launch_bounds__(128) k_trans(
    const float* __restrict__ h,
    const float* __restrict__ Wl, const float* __restrict__ bl,
    const float* __restrict__ Wr, const float* __restrict__ br,
    __half* __restrict__ xl, float* __restrict__ xr) {
    __shared__ float s_h[32 * kC];
    int j = threadIdx.x;                  // feature 0..127
    int hd = j >> 5, c = j & 31;
    float wl[kC], wr[kC];
    #pragma unroll
    for (int k = 0; k < kC; ++k) { wl[k] = Wl[k * kHC + j]; wr[k] = Wr[k * kHC + j]; }
    float blj = bl[j], brj = br[j];
    int n0 = blockIdx.x * 32;
    int nn = min(32, kNodes - n0);
    for (int i = j; i < nn * kC; i += 128) s_h[i] = h[n0 * kC + i];
    __syncthreads();
    for (int n = 0; n < nn; ++n) {
        const float4* h4 = (const float4*)(s_h + n * kC);
        float al = blj, ar = brj;
        #pragma unroll
        for (int kq = 0; kq < 8; ++kq) {
            float4 hv = h4[kq];
            al += hv.x * wl[kq*4] + hv.y * wl[kq*4+1] + hv.z * wl[kq*4+2] + hv.w * wl[kq*4+3];
            ar += hv.x * wr[kq*4] + hv.y * wr[kq*4+1] + hv.z * wr[kq*4+2] + hv.w * wr[kq*4+3];
        }
        int node = n0 + n;
        xl[(long)hd * (kNodes * kC) + (long)node * kC + c] = __float2half(al);
        xr[(long)node * kHC + j] = ar;
    }
}

// ---- CSR build (dst is layer-invariant: built ONCE)
__global__ void __launch_bounds__(256) k_hist(const int* __restrict__ dst, int* __restrict__ deg) {
    int e = blockIdx.x * 256 + threadIdx.x;
    if (e < kNE) atomicAdd(&deg[dst[e]], 1);
}

__global__ void __launch_bounds__(256) k_scan1(const int* __restrict__ deg,
                                               int* __restrict__ excl, int* __restrict__ bsum) {
    __shared__ int s[256];
    int t = threadIdx.x;
    int i = blockIdx.x * 256 + t;
    int v = (i < kNodes) ? deg[i] : 0;
    s[t] = v;
    __syncthreads();
    for (int o = 1; o < 256; o <<= 1) {
        int tv = (t >= o) ? s[t - o] : 0;
        __syncthreads();
        s[t] += tv;
        __syncthreads();
    }
    if (i < kNodes) excl[i] = s[t] - v;
    if (t == 255) bsum[blockIdx.x] = s[255];
}

__global__ void __launch_bounds__(256) k_scan2(int* __restrict__ bsum, int nb) {
    __shared__ int s[256];
    int t = threadIdx.x;
    int v = (t < nb) ? bsum[t] : 0;
    s[t] = v;
    __syncthreads();
    for (int o = 1; o < 256; o <<= 1) {
        int tv = (t >= o) ? s[t - o] : 0;
        __syncthreads();
        s[t] += tv;
        __syncthreads();
    }
    if (t < nb) bsum[t] = s[t];
}

__global__ void __launch_bounds__(256) k_scan3(int* __restrict__ excl, const int* __restrict__ bsum) {
    int i = blockIdx.x * 256 + threadIdx.x;
    if (i >= kNodes) return;
    if (blockIdx.x > 0) excl[i] += bsum[blockIdx.x - 1];
}

__global__ void __launch_bounds__(256) k_reorder(
    const int* __restrict__ src, const int* __restrict__ dst, const float* __restrict__ ea,
    const int* __restrict__ rowptr, int* __restrict__ cur,
    int* __restrict__ esrc, float* __restrict__ eea) {
    int e = blockIdx.x * 256 + threadIdx.x;
    if (e >= kNE) return;
    int d = dst[e];
    int pos = rowptr[d] + atomicAdd(&cur[d], 1);
    esrc[pos] = src[e];
    eea[pos]  = ea[e];
}

// ---- K3: fused edge phase, head-split + XCD swizzle. 32-lane group = (dst, head).
// xl is head-major: per-head slice 3.2 MB fits one XCD's 4 MB L2. Edge metadata
// broadcast via shfl (no LDS, no barriers). ps/pq indexed by (dst*kH + head).
__global__ void __launch_bounds__(256) k_edge(
    const int* __restrict__ rowptr, const int* __restrict__ deg,
    const int* __restrict__ esrc, const float* __restrict__ eea,
    const __half* __restrict__ xl, float* __restrict__ xrg,
    const float* __restrict__ We, const float* __restrict__ att,
    const float* __restrict__ gat_b, float* __restrict__ ps, float* __restrict__ pq) {
    int b = blockIdx.x;
    int xcd = b & 7;
    int head = xcd >> 1;                  // heads pinned to XCD pairs
    int sub = (b >> 3) * 2 + (xcd & 1);   // 0..6249
    int t = threadIdx.x;
    int grp = t >> 5, c = t & 31;
    int d = sub * 8 + grp;
    const __half* xh = xl + (long)head * (kNodes * kC);
    int fj = head * kC + c;               // feature index in 128-wide layout
    float r_xr  = xrg[(long)d * kHC + fj];
    float r_We  = We[fj];
    float r_att = att[fj];
    float xlo   = __half2float(xh[(long)d * kC + c]);

    // self loop (ea = 0)
    float z = xlo + r_xr;
    z = (z > 0.f) ? z : kSlope * z;
    float p = z * r_att;
    #pragma unroll
    for (int mm = 1; mm < 32; mm <<= 1) p += __shfl_xor(p, mm);
    float ex = __expf(p - kShift);
    float l = ex, o = ex * xlo;

    int base = rowptr[d], cnt = deg[d];
    for (int eoff = 0; eoff < cnt; eoff += 32) {
        int cc = min(32, cnt - eoff);
        int pos = base + eoff + c;
        int   msrc = (c < cc) ? esrc[pos] : 0;
        float mea  = (c < cc) ? eea[pos] : 0.f;
        int e = 0;
        for (; e + 4 <= cc; e += 4) {
            int   s0 = __shfl(msrc, e, 32),   s1 = __shfl(msrc, e+1, 32);
            int   s2 = __shfl(msrc, e+2, 32), s3 = __shfl(msrc, e+3, 32);
            float a0 = __shfl(mea, e, 32),    a1 = __shfl(mea, e+1, 32);
            float a2 = __shfl(mea, e+2, 32),  a3 = __shfl(mea, e+3, 32);
            float x0 = __half2float(xh[(long)s0 * kC + c]);
            float x1 = __half2float(xh[(long)s1 * kC + c]);
            float x2 = __half2float(xh[(long)s2 * kC + c]);
            float x3 = __half2float(xh[(long)s3 * kC + c]);
            float z0 = x0 + r_xr + a0 * r_We; z0 = (z0 > 0.f) ? z0 : kSlope * z0;
            float z1 = x1 + r_xr + a1 * r_We; z1 = (z1 > 0.f) ? z1 : kSlope * z1;
            float z2 = x2 + r_xr + a2 * r_We; z2 = (z2 > 0.f) ? z2 : kSlope * z2;
            float z3 = x3 + r_xr + a3 * r_We; z3 = (z3 > 0.f) ? z3 : kSlope * z3;
            float p0 = z0 * r_att, p1 = z1 * r_att, p2 = z2 * r_att, p3 = z3 * r_att;
            #pragma unroll
            for (int mm = 1; mm < 32; mm <<= 1) {
                p0 += __shfl_xor(p0, mm); p1 += __shfl_xor(p1, mm);
                p2 += __shfl_xor(p2, mm); p3 += __shfl_xor(p3, mm);
            }
            float e0 = __expf(p0 - kShift), e1 = __expf(p1 - kShift);
            float e2 = __expf(p2 - kShift), e3 = __expf(p3 - kShift);
            l += e0 + e1 + e2 + e3;
            o += e0 * x0 + e1 * x1 + e2 * x2 + e3 * x3;
        }
        for (; e < cc; ++e) {
            int   se = __shfl(msrc, e, 32);
            float ae = __shfl(mea, e, 32);
            float xe = __half2float(xh[(long)se * kC + c]);
            float ze = xe + r_xr + ae * r_We;
            ze = (ze > 0.f) ? ze : kSlope * ze;
            float pe = ze * r_att;
            #pragma unroll
            for (int mm = 1; mm < 32; mm <<= 1) pe += __shfl_xor(pe, mm);
            float exe = __expf(pe - kShift);
            l += exe;
            o += exe * xe;
        }
    }
    float v = o / l;
    xrg[(long)d * kHC + fj] = v;          // g overwrites xr (row-private)
    // fused graph-LN partials over (v + gat_b), per (dst, head)
    float vb = v + gat_b[fj];
    float s = vb, q = vb * vb;
    #pragma unroll
    for (int mm = 1; mm < 32; mm <<= 1) { s += __shfl_xor(s, mm); q += __shfl_xor(q, mm); }
    if (c == 0) { ps[d * kH + head] = s; pq[d * kH + head] = q; }
}

// ---- K4: reduce per-(dst,head) partials -> stats[2].
__global__ void __launch_bounds__(1024) k_statsr(
    const float* __restrict__ ps, const float* __restrict__ pq, float* __restrict__ stats) {
    __shared__ float rs[1024], rq[1024];
    int t = threadIdx.x;
    float s = 0.f, q = 0.f;
    for (int i = t; i < kNodes * kH; i += 1024) { s += ps[i]; q += pq[i]; }
    rs[t] = s; rq[t] = q;
    __syncthreads();
    for (int o = 512; o > 0; o >>= 1) {
        if (t < o) { rs[t] += rs[t + o]; rq[t] += rq[t + o]; }
        __syncthreads();
    }
    if (t == 0) { stats[0] = rs[0]; stats[1] = rq[0]; }
}

// ---- K5: h = relu(node_ln(relu(graph_ln(g+gat_b)) @ lin_w + lin_b)); jk_out = max(jk_in, h)
__global__ void __launch_bounds__(256) k_post(
    const float* __restrict__ g, const float* __restrict__ gat_b,
    const float* __restrict__ ln1w, const float* __restrict__ ln1b,
    const float* __restrict__ linw, const float* __restrict__ linb,
    const float* __restrict__ ln2w, const float* __restrict__ ln2b,
    const float* __restrict__ stats, const float* __restrict__ jk_in,
    float* __restrict__ h, float* __restrict__ jk_out) {
    __shared__ float s_lw[kHC * kC];      // 16 KB
    __shared__ float s_vb[8 * kHC];       // 4 KB
    int t = threadIdx.x;
    int n0 = blockIdx.x * 8;
    const float inv = 1.f / ((float)kNodes * kHC);
    float mean = stats[0] * inv;
    float var  = stats[1] * inv - mean * mean;
    float rstd = rsqrtf(var + kEps);
    for (int i = t; i < kHC * kC; i += 256) s_lw[i] = linw[i];
    for (int i = t; i < 8 * kHC; i += 256) {
        int node = n0 + (i >> 7), f = i & 127;
        float a = (g[(long)node * kHC + f] + gat_b[f] - mean) * rstd * ln1w[f] + ln1b[f];
        s_vb[i] = fmaxf(a, 0.f);
    }
    __syncthreads();
    int n = t >> 5, c = t & 31;
    int node = n0 + n;
    float acc = linb[c];
    #pragma unroll 8
    for (int k = 0; k < kHC; ++k) acc += s_vb[n * kHC + k] * s_lw[k * kC + c];
    float m = acc;
    #pragma unroll
    for (int mm = 1; mm < 32; mm <<= 1) m += __shfl_xor(m, mm);
    m *= (1.f / kC);
    float dd = acc - m;
    float q = dd * dd;
    #pragma unroll
    for (int mm = 1; mm < 32; mm <<= 1) q += __shfl_xor(q, mm);
    q *= (1.f / kC);
    float out = dd * rsqrtf(q + kEps) * ln2w[c] + ln2b[c];
    out = fmaxf(out, 0.f);
    h[node * kC + c] = out;
    jk_out[node * kC + c] = fmaxf(jk_in[node * kC + c], out);
}

extern "C" void kernel_launch(void* const* d_in, const int* in_sizes, int n_in,
                              void* d_out, int out_size, void* d_ws, size_t ws_size,
                              hipStream_t stream) {
    (void)in_sizes; (void)n_in; (void)out_size; (void)ws_size;
    const float* x     = (const float*)d_in[0];
    const int*   ei    = (const int*)d_in[1];
    const int*   src   = ei;
    const int*   dst   = ei + kNE;
    const float* ea    = (const float*)d_in[2];
    const float* W_emb = (const float*)d_in[3];
    const float* b_emb = (const float*)d_in[4];
    const float* ln0w  = (const float*)d_in[5];
    const float* ln0b  = (const float*)d_in[6];
    const float* Wl    = (const float*)d_in[7];
    const float* bl    = (const float*)d_in[8];
    const float* Wr    = (const float*)d_in[9];
    const float* br    = (const float*)d_in[10];
    const float* We    = (const float*)d_in[11];
    const float* att   = (const float*)d_in[12];
    const float* gat_b = (const float*)d_in[13];
    const float* ln1w  = (const float*)d_in[14];
    const float* ln1b  = (const float*)d_in[15];
    const float* linw  = (const float*)d_in[16];
    const float* linb  = (const float*)d_in[17];
    const float* ln2w  = (const float*)d_in[18];
    const float* ln2b  = (const float*)d_in[19];

    char* wsb = (char*)d_ws;
    float*  h      = (float*)(wsb);                 // 6.4e6 B
    float*  jk     = (float*)(wsb +  6400000);      // 6.4e6 B
    float*  xrg    = (float*)(wsb + 12800000);      // 25.6e6 B (xr, later g)
    __half* xl     = (__half*)(wsb + 38400000);     // 12.8e6 B head-major
    int*    esrc   = (int*)(wsb + 51200000);        // 3.2e6 B
    float*  eea    = (float*)(wsb + 54400000);      // 3.2e6 B
    int*    deg    = (int*)(wsb + 57600000);        // 0.2e6 B
    int*    cur    = (int*)(wsb + 57800000);        // 0.2e6 B
    int*    rowptr = (int*)(wsb + 58000000);        // 0.2e6 B
    int*    bsum   = (int*)(wsb + 58200000);        // 1 KB
    float*  stats  = (float*)(wsb + 58201024);      // 8 B
    float*  ps     = (float*)(wsb + 58300000);      // 0.8e6 B (N*H)
    float*  pq     = (float*)(wsb + 59100000);      // 0.8e6 B
    // end = 59.9e6 B

    const int scanBlocks  = (kNodes + 255) / 256;        // 196
    const int embedBlocks = kNodes / 8;                  // 6250 exact
    const int transBlocks = (kNodes + 31) / 32;          // 1563
    const int eBlocks     = (kNE + 255) / 256;
    const int edgeBlocks  = kNodes / 2;                  // 25000: 8 (dst,head) groups/block
    const int postBlocks  = kNodes / 8;                  // 6250 exact

    hipLaunchKernelGGL(k_embed, dim3(embedBlocks), dim3(256), 0, stream,
                       x, W_emb, b_emb, ln0w, ln0b, h, jk);
    // CSR build (once; dst is layer-invariant)
    hipLaunchKernelGGL(k_fill0, dim3((2 * kNodes + 255) / 256), dim3(256), 0, stream,
                       (unsigned*)deg, 2 * kNodes);      // deg + cur
    hipLaunchKernelGGL(k_hist, dim3(eBlocks), dim3(256), 0, stream, dst, deg);
    hipLaunchKernelGGL(k_scan1, dim3(scanBlocks), dim3(256), 0, stream, deg, rowptr, bsum);
    hipLaunchKernelGGL(k_scan2, dim3(1), dim3(256), 0, stream, bsum, scanBlocks);
    hipLaunchKernelGGL(k_scan3, dim3(scanBlocks), dim3(256), 0, stream, rowptr, bsum);
    hipLaunchKernelGGL(k_reorder, dim3(eBlocks), dim3(256), 0, stream,
                       src, dst, ea, rowptr, cur, esrc, eea);
    for (int l = 0; l < 2; ++l) {
        hipLaunchKernelGGL(k_trans, dim3(transBlocks), dim3(128), 0, stream,
                           h, Wl + l * kC * kHC, bl + l * kHC,
                           Wr + l * kC * kHC, br + l * kHC, xl, xrg);
        hipLaunchKernelGGL(k_edge, dim3(edgeBlocks), dim3(256), 0, stream,
                           rowptr, deg, esrc, eea, xl, xrg,
                           We + l * kHC, att + l * kH * kC, gat_b + l * kHC, ps, pq);
        hipLaunchKernelGGL(k_statsr, dim3(1), dim3(1024), 0, stream, ps, pq, stats);
        hipLaunchKernelGGL(k_post, dim3(postBlocks), dim3(256), 0, stream,
                           xrg, gat_b + l * kHC, ln1w + l * kHC, ln1b + l * kHC,
                           linw + l * kHC * kC, linb + l * kC,
                           ln2w + l * kC, ln2b + l * kC, stats, jk,
                           h, (l == 1) ? (float*)d_out : jk);
    }
}

// Round 12
// 686.026 us; speedup vs baseline: 1.1591x; 1.1591x over previous
//
#include <hip/hip_runtime.h>
#include <hip/hip_fp16.h>

constexpr int kNodes = 50000;
constexpr int kNE    = 800000;            // edges before self loops
constexpr int kFin   = 256;
constexpr int kC     = 32;
constexpr int kH     = 4;
constexpr int kHC    = 128;               // kH * kC
constexpr int kCH    = 32;                // edge chunk per block iteration
constexpr float kEps   = 1e-5f;
constexpr float kSlope = 0.2f;
constexpr float kShift = 8.0f;            // softmax-invariant global shift

// ---- zero-fill
__global__ void __launch_bounds__(256) k_fill0(unsigned* __restrict__ p, int n) {
    int i = blockIdx.x * 256 + threadIdx.x;
    if (i < n) p[i] = 0u;
}

// ---- K1: h0 = relu(node_ln(x @ W_emb + b_emb)); jk = h0.
// Wave per node, zero LDS: lane=(c,half); x via 2-address wave broadcast,
// W via one 128B line per k (L1-hot); halves + LN via shfl.
__global__ void __launch_bounds__(256) k_embed(
    const float* __restrict__ x, const float* __restrict__ W, const float* __restrict__ b,
    const float* __restrict__ lnw, const float* __restrict__ lnb,
    float* __restrict__ h, float* __restrict__ jk) {
    int node = blockIdx.x * 4 + (threadIdx.x >> 6);
    int lane = threadIdx.x & 63;
    int c = lane & 31, half = lane >> 5;
    const float* xp = x + (long)node * kFin + half * 128;
    const float* wp = W + (half * 128) * kC + c;
    float a0 = 0.f, a1 = 0.f, a2 = 0.f, a3 = 0.f;
    #pragma unroll 4
    for (int k = 0; k < 128; k += 4) {
        a0 += xp[k]     * wp[(k)     * kC];
        a1 += xp[k + 1] * wp[(k + 1) * kC];
        a2 += xp[k + 2] * wp[(k + 2) * kC];
        a3 += xp[k + 3] * wp[(k + 3) * kC];
    }
    float acc = (a0 + a1) + (a2 + a3);
    acc += __shfl_xor(acc, 32);           // combine K-halves
    float y = acc + b[c];
    float m = y;
    #pragma unroll
    for (int o = 1; o < 32; o <<= 1) m += __shfl_xor(m, o);
    m *= (1.f / kC);
    float xc = y - m;
    float v = xc * xc;
    #pragma unroll
    for (int o = 1; o < 32; o <<= 1) v += __shfl_xor(v, o);
    v *= (1.f / kC);
    float out = xc * rsqrtf(v + kEps) * lnw[c] + lnb[c];
    out = fmaxf(out, 0.f);
    if (half == 0) { h[node * kC + c] = out; jk[node * kC + c] = out; }
}

// ---- K2: xl = h@Wl + bl (fp16) ; xr = h@Wr + br (fp32). (r10 version)
__global__ void __launch_bounds__(128) k_trans(
    const float* __restrict__ h,
    const float* __restrict__ Wl, const float* __restrict__ bl,
    const float* __restrict__ Wr, const float* __restrict__ br,
    __half* __restrict__ xl, float* __restrict__ xr) {
    __shared__ float s_h[32 * kC];
    int j = threadIdx.x;                  // feature 0..127
    float wl[kC], wr[kC];
    #pragma unroll
    for (int k = 0; k < kC; ++k) { wl[k] = Wl[k * kHC + j]; wr[k] = Wr[k * kHC + j]; }
    float blj = bl[j], brj = br[j];
    int n0 = blockIdx.x * 32;
    int nn = min(32, kNodes - n0);
    for (int i = j; i < nn * kC; i += 128) s_h[i] = h[n0 * kC + i];
    __syncthreads();
    for (int n = 0; n < nn; ++n) {
        const float4* h4 = (const float4*)(s_h + n * kC);
        float al = blj, ar = brj;
        #pragma unroll
        for (int kq = 0; kq < 8; ++kq) {
            float4 hv = h4[kq];
            al += hv.x * wl[kq*4] + hv.y * wl[kq*4+1] + hv.z * wl[kq*4+2] + hv.w * wl[kq*4+3];
            ar += hv.x * wr[kq*4] + hv.y * wr[kq*4+1] + hv.z * wr[kq*4+2] + hv.w * wr[kq*4+3];
        }
        long g = (long)(n0 + n) * kHC + j;
        xl[g] = __float2half(al);
        xr[g] = ar;
    }
}

// ---- CSR build (dst is layer-invariant: built ONCE)
__global__ void __launch_bounds__(256) k_hist(const int* __restrict__ dst, int* __restrict__ deg) {
    int e = blockIdx.x * 256 + threadIdx.x;
    if (e < kNE) atomicAdd(&deg[dst[e]], 1);
}

__global__ void __launch_bounds__(256) k_scan1(const int* __restrict__ deg,
                                               int* __restrict__ excl, int* __restrict__ bsum) {
    __shared__ int s[256];
    int t = threadIdx.x;
    int i = blockIdx.x * 256 + t;
    int v = (i < kNodes) ? deg[i] : 0;
    s[t] = v;
    __syncthreads();
    for (int o = 1; o < 256; o <<= 1) {
        int tv = (t >= o) ? s[t - o] : 0;
        __syncthreads();
        s[t] += tv;
        __syncthreads();
    }
    if (i < kNodes) excl[i] = s[t] - v;
    if (t == 255) bsum[blockIdx.x] = s[255];
}

__global__ void __launch_bounds__(256) k_scan2(int* __restrict__ bsum, int nb) {
    __shared__ int s[256];
    int t = threadIdx.x;
    int v = (t < nb) ? bsum[t] : 0;
    s[t] = v;
    __syncthreads();
    for (int o = 1; o < 256; o <<= 1) {
        int tv = (t >= o) ? s[t - o] : 0;
        __syncthreads();
        s[t] += tv;
        __syncthreads();
    }
    if (t < nb) bsum[t] = s[t];
}

__global__ void __launch_bounds__(256) k_scan3(int* __restrict__ excl, const int* __restrict__ bsum) {
    int i = blockIdx.x * 256 + threadIdx.x;
    if (i >= kNodes) return;
    if (blockIdx.x > 0) excl[i] += bsum[blockIdx.x - 1];
}

__global__ void __launch_bounds__(256) k_reorder(
    const int* __restrict__ src, const int* __restrict__ dst, const float* __restrict__ ea,
    const int* __restrict__ rowptr, int* __restrict__ cur,
    int* __restrict__ esrc, float* __restrict__ eea) {
    int e = blockIdx.x * 256 + threadIdx.x;
    if (e >= kNE) return;
    int d = dst[e];
    int pos = rowptr[d] + atomicAdd(&cur[d], 1);
    esrc[pos] = src[e];
    eea[pos]  = ea[e];
}

// ---- K3: fused edge phase, feature-parallel (r10 layout), 8-wide ILP.
__global__ void __launch_bounds__(128) k_edge(
    const int* __restrict__ rowptr, const int* __restrict__ deg,
    const int* __restrict__ esrc, const float* __restrict__ eea,
    const __half* __restrict__ xl, float* __restrict__ xrg,
    const float* __restrict__ We, const float* __restrict__ att,
    const float* __restrict__ gat_b, float* __restrict__ ps, float* __restrict__ pq) {
    __shared__ int   s_src[kCH];
    __shared__ float s_ea[kCH];
    __shared__ float s_red[4];
    int d = blockIdx.x;
    int j = threadIdx.x;                  // feature 0..127; head = j>>5
    long rowb = (long)d * kHC;
    float r_xr  = xrg[rowb + j];
    float r_We  = We[j];
    float r_att = att[j];
    float xlo   = __half2float(xl[rowb + j]);

    // self loop (ea = 0)
    float z = xlo + r_xr;
    z = (z > 0.f) ? z : kSlope * z;
    float p = z * r_att;
    #pragma unroll
    for (int mm = 1; mm < 32; mm <<= 1) p += __shfl_xor(p, mm);
    float ex = __expf(p - kShift);
    float l = ex, o = ex * xlo;

    int base = rowptr[d], cnt = deg[d];
    for (int eoff = 0; eoff < cnt; eoff += kCH) {
        int cc = min(kCH, cnt - eoff);
        __syncthreads();
        if (j < cc) { s_src[j] = esrc[base + eoff + j]; s_ea[j] = eea[base + eoff + j]; }
        __syncthreads();
        int e = 0;
        for (; e + 8 <= cc; e += 8) {
            float xv[8], pv[8];
            #pragma unroll
            for (int u = 0; u < 8; ++u)
                xv[u] = __half2float(xl[(long)s_src[e + u] * kHC + j]);
            #pragma unroll
            for (int u = 0; u < 8; ++u) {
                float zz = xv[u] + r_xr + s_ea[e + u] * r_We;
                zz = (zz > 0.f) ? zz : kSlope * zz;
                pv[u] = zz * r_att;
            }
            #pragma unroll
            for (int mm = 1; mm < 32; mm <<= 1) {
                #pragma unroll
                for (int u = 0; u < 8; ++u) pv[u] += __shfl_xor(pv[u], mm);
            }
            #pragma unroll
            for (int u = 0; u < 8; ++u) {
                float ee = __expf(pv[u] - kShift);
                l += ee;
                o += ee * xv[u];
            }
        }
        for (; e < cc; ++e) {
            float xe = __half2float(xl[(long)s_src[e] * kHC + j]);
            float ze = xe + r_xr + s_ea[e] * r_We;
            ze = (ze > 0.f) ? ze : kSlope * ze;
            float pe = ze * r_att;
            #pragma unroll
            for (int mm = 1; mm < 32; mm <<= 1) pe += __shfl_xor(pe, mm);
            float exe = __expf(pe - kShift);
            l += exe;
            o += exe * xe;
        }
    }
    float v = o / l;
    xrg[rowb + j] = v;                    // g overwrites xr (row-private)
    // fused graph-LN partials over (v + gat_b)
    float vb = v + gat_b[j];
    float s = vb, q = vb * vb;
    #pragma unroll
    for (int off = 1; off < 64; off <<= 1) { s += __shfl_xor(s, off); q += __shfl_xor(q, off); }
    if ((j & 63) == 0) { s_red[(j >> 6) * 2] = s; s_red[(j >> 6) * 2 + 1] = q; }
    __syncthreads();
    if (j == 0) { ps[d] = s_red[0] + s_red[2]; pq[d] = s_red[1] + s_red[3]; }
}

// ---- K4: reduce per-node partials -> stats[2].
__global__ void __launch_bounds__(1024) k_statsr(
    const float* __restrict__ ps, const float* __restrict__ pq, float* __restrict__ stats) {
    __shared__ float rs[1024], rq[1024];
    int t = threadIdx.x;
    float s = 0.f, q = 0.f;
    for (int i = t; i < kNodes; i += 1024) { s += ps[i]; q += pq[i]; }
    rs[t] = s; rq[t] = q;
    __syncthreads();
    for (int o = 512; o > 0; o >>= 1) {
        if (t < o) { rs[t] += rs[t + o]; rq[t] += rq[t + o]; }
        __syncthreads();
    }
    if (t == 0) { stats[0] = rs[0]; stats[1] = rq[0]; }
}

// ---- K5: h = relu(node_ln(relu(graph_ln(g+gat_b)) @ lin_w + lin_b)); jk_out = max(jk_in, h)
__global__ void __launch_bounds__(256) k_post(
    const float* __restrict__ g, const float* __restrict__ gat_b,
    const float* __restrict__ ln1w, const float* __restrict__ ln1b,
    const float* __restrict__ linw, const float* __restrict__ linb,
    const float* __restrict__ ln2w, const float* __restrict__ ln2b,
    const float* __restrict__ stats, const float* __restrict__ jk_in,
    float* __restrict__ h, float* __restrict__ jk_out) {
    __shared__ float s_lw[kHC * kC];      // 16 KB
    __shared__ float s_vb[8 * kHC];       // 4 KB
    int t = threadIdx.x;
    int n0 = blockIdx.x * 8;
    const float inv = 1.f / ((float)kNodes * kHC);
    float mean = stats[0] * inv;
    float var  = stats[1] * inv - mean * mean;
    float rstd = rsqrtf(var + kEps);
    for (int i = t; i < kHC * kC; i += 256) s_lw[i] = linw[i];
    for (int i = t; i < 8 * kHC; i += 256) {
        int node = n0 + (i >> 7), f = i & 127;
        float a = (g[(long)node * kHC + f] + gat_b[f] - mean) * rstd * ln1w[f] + ln1b[f];
        s_vb[i] = fmaxf(a, 0.f);
    }
    __syncthreads();
    int n = t >> 5, c = t & 31;
    int node = n0 + n;
    float acc = linb[c];
    #pragma unroll 8
    for (int k = 0; k < kHC; ++k) acc += s_vb[n * kHC + k] * s_lw[k * kC + c];
    float m = acc;
    #pragma unroll
    for (int mm = 1; mm < 32; mm <<= 1) m += __shfl_xor(m, mm);
    m *= (1.f / kC);
    float dd = acc - m;
    float q = dd * dd;
    #pragma unroll
    for (int mm = 1; mm < 32; mm <<= 1) q += __shfl_xor(q, mm);
    q *= (1.f / kC);
    float out = dd * rsqrtf(q + kEps) * ln2w[c] + ln2b[c];
    out = fmaxf(out, 0.f);
    h[node * kC + c] = out;
    jk_out[node * kC + c] = fmaxf(jk_in[node * kC + c], out);
}

extern "C" void kernel_launch(void* const* d_in, const int* in_sizes, int n_in,
                              void* d_out, int out_size, void* d_ws, size_t ws_size,
                              hipStream_t stream) {
    (void)in_sizes; (void)n_in; (void)out_size; (void)ws_size;
    const float* x     = (const float*)d_in[0];
    const int*   ei    = (const int*)d_in[1];
    const int*   src   = ei;
    const int*   dst   = ei + kNE;
    const float* ea    = (const float*)d_in[2];
    const float* W_emb = (const float*)d_in[3];
    const float* b_emb = (const float*)d_in[4];
    const float* ln0w  = (const float*)d_in[5];
    const float* ln0b  = (const float*)d_in[6];
    const float* Wl    = (const float*)d_in[7];
    const float* bl    = (const float*)d_in[8];
    const float* Wr    = (const float*)d_in[9];
    const float* br    = (const float*)d_in[10];
    const float* We    = (const float*)d_in[11];
    const float* att   = (const float*)d_in[12];
    const float* gat_b = (const float*)d_in[13];
    const float* ln1w  = (const float*)d_in[14];
    const float* ln1b  = (const float*)d_in[15];
    const float* linw  = (const float*)d_in[16];
    const float* linb  = (const float*)d_in[17];
    const float* ln2w  = (const float*)d_in[18];
    const float* ln2b  = (const float*)d_in[19];

    char* wsb = (char*)d_ws;
    float*  h      = (float*)(wsb);                 // 6.4e6 B
    float*  jk     = (float*)(wsb +  6400000);      // 6.4e6 B
    float*  xrg    = (float*)(wsb + 12800000);      // 25.6e6 B (xr, later g)
    __half* xl     = (__half*)(wsb + 38400000);     // 12.8e6 B
    int*    esrc   = (int*)(wsb + 51200000);        // 3.2e6 B
    float*  eea    = (float*)(wsb + 54400000);      // 3.2e6 B
    int*    deg    = (int*)(wsb + 57600000);        // 0.2e6 B
    int*    cur    = (int*)(wsb + 57800000);        // 0.2e6 B
    int*    rowptr = (int*)(wsb + 58000000);        // 0.2e6 B
    int*    bsum   = (int*)(wsb + 58200000);        // 1 KB
    float*  stats  = (float*)(wsb + 58201024);      // 8 B
    float*  ps     = (float*)(wsb + 58300000);      // 0.2e6 B
    float*  pq     = (float*)(wsb + 58500000);      // 0.2e6 B

    const int scanBlocks  = (kNodes + 255) / 256;        // 196
    const int embedBlocks = kNodes / 4;                  // 12500 exact
    const int transBlocks = (kNodes + 31) / 32;          // 1563
    const int eBlocks     = (kNE + 255) / 256;
    const int postBlocks  = kNodes / 8;                  // 6250 exact

    hipLaunchKernelGGL(k_embed, dim3(embedBlocks), dim3(256), 0, stream,
                       x, W_emb, b_emb, ln0w, ln0b, h, jk);
    // CSR build (once; dst is layer-invariant)
    hipLaunchKernelGGL(k_fill0, dim3((2 * kNodes + 255) / 256), dim3(256), 0, stream,
                       (unsigned*)deg, 2 * kNodes);      // deg + cur
    hipLaunchKernelGGL(k_hist, dim3(eBlocks), dim3(256), 0, stream, dst, deg);
    hipLaunchKernelGGL(k_scan1, dim3(scanBlocks), dim3(256), 0, stream, deg, rowptr, bsum);
    hipLaunchKernelGGL(k_scan2, dim3(1), dim3(256), 0, stream, bsum, scanBlocks);
    hipLaunchKernelGGL(k_scan3, dim3(scanBlocks), dim3(256), 0, stream, rowptr, bsum);
    hipLaunchKernelGGL(k_reorder, dim3(eBlocks), dim3(256), 0, stream,
                       src, dst, ea, rowptr, cur, esrc, eea);
    for (int l = 0; l < 2; ++l) {
        hipLaunchKernelGGL(k_trans, dim3(transBlocks), dim3(128), 0, stream,
                           h, Wl + l * kC * kHC, bl + l * kHC,
                           Wr + l * kC * kHC, br + l * kHC, xl, xrg);
        hipLaunchKernelGGL(k_edge, dim3(kNodes), dim3(128), 0, stream,
                           rowptr, deg, esrc, eea, xl, xrg,
                           We + l * kHC, att + l * kH * kC, gat_b + l * kHC, ps, pq);
        hipLaunchKernelGGL(k_statsr, dim3(1), dim3(1024), 0, stream, ps, pq, stats);
        hipLaunchKernelGGL(k_post, dim3(postBlocks), dim3(256), 0, stream,
                           xrg, gat_b + l * kHC, ln1w + l * kHC, ln1b + l * kHC,
                           linw + l * kHC * kC, linb + l * kC,
                           ln2w + l * kC, ln2b + l * kC, stats, jk,
                           h, (l == 1) ? (float*)d_out : jk);
    }
}

// Round 13
// 630.127 us; speedup vs baseline: 1.2619x; 1.0887x over previous
//
#include <hip/hip_runtime.h>
#include <hip/hip_fp16.h>

constexpr int kNodes = 50000;
constexpr int kNE    = 800000;            // edges before self loops
constexpr int kFin   = 256;
constexpr int kC     = 32;
constexpr int kH     = 4;
constexpr int kHC    = 128;               // kH * kC
constexpr int kCH    = 32;                // edge chunk per block iteration
constexpr int kTN    = 16;                // nodes per k_embed block
constexpr int kWP    = 258;               // padded sWt row (2-way LDS alias = free)
constexpr float kEps   = 1e-5f;
constexpr float kSlope = 0.2f;
constexpr float kShift = 8.0f;            // softmax-invariant global shift

// ---- zero-fill
__global__ void __launch_bounds__(256) k_fill0(unsigned* __restrict__ p, int n) {
    int i = blockIdx.x * 256 + threadIdx.x;
    if (i < n) p[i] = 0u;
}

// ---- K1: h0 = relu(node_ln(x @ W_emb + b_emb)); jk = h0.
// 16 nodes/block; x staged (16KB), W staged TRANSPOSED pad-258 (33KB).
// Thread t = (c, n2): computes nodes n2 and n2+8. Inner: float4 x-broadcast +
// 2x float2 W-row reads per 4k. LN via 32-lane shfl.
__global__ void __launch_bounds__(256) k_embed(
    const float* __restrict__ x, const float* __restrict__ W, const float* __restrict__ b,
    const float* __restrict__ lnw, const float* __restrict__ lnb,
    float* __restrict__ h, float* __restrict__ jk) {
    __shared__ float sx[kTN * kFin];      // 16 KB
    __shared__ float sWt[kC * kWP];       // 33 KB
    int t = threadIdx.x;
    int n0 = blockIdx.x * kTN;            // 50000 = 3125 * 16 exact
    for (int i = t; i < kFin * kC; i += 256) {
        int k = i >> 5, c = i & 31;
        sWt[c * kWP + k] = W[i];
    }
    const float* xg = x + (long)n0 * kFin;
    for (int i = t; i < kTN * kFin; i += 256) sx[i] = xg[i];
    __syncthreads();
    int c = t & 31, n2 = t >> 5;          // n2 = 0..7
    const float* xa = sx + n2 * kFin;
    const float* xb = sx + (n2 + 8) * kFin;
    const float* wrow = sWt + c * kWP;
    float acc0 = 0.f, acc1 = 0.f;
    #pragma unroll 8
    for (int k = 0; k < kFin; k += 4) {
        float4 x0 = *(const float4*)(xa + k);
        float4 x1 = *(const float4*)(xb + k);
        float2 w0 = *(const float2*)(wrow + k);
        float2 w1 = *(const float2*)(wrow + k + 2);
        acc0 += x0.x * w0.x + x0.y * w0.y + x0.z * w1.x + x0.w * w1.y;
        acc1 += x1.x * w0.x + x1.y * w0.y + x1.z * w1.x + x1.w * w1.y;
    }
    float bc = b[c], lw = lnw[c], lb = lnb[c];
    // node n2
    {
        float y = acc0 + bc;
        float m = y;
        #pragma unroll
        for (int o = 1; o < 32; o <<= 1) m += __shfl_xor(m, o);
        m *= (1.f / kC);
        float xc = y - m, v = xc * xc;
        #pragma unroll
        for (int o = 1; o < 32; o <<= 1) v += __shfl_xor(v, o);
        v *= (1.f / kC);
        float out = fmaxf(xc * rsqrtf(v + kEps) * lw + lb, 0.f);
        int node = n0 + n2;
        h[node * kC + c] = out;
        jk[node * kC + c] = out;
    }
    // node n2 + 8
    {
        float y = acc1 + bc;
        float m = y;
        #pragma unroll
        for (int o = 1; o < 32; o <<= 1) m += __shfl_xor(m, o);
        m *= (1.f / kC);
        float xc = y - m, v = xc * xc;
        #pragma unroll
        for (int o = 1; o < 32; o <<= 1) v += __shfl_xor(v, o);
        v *= (1.f / kC);
        float out = fmaxf(xc * rsqrtf(v + kEps) * lw + lb, 0.f);
        int node = n0 + n2 + 8;
        h[node * kC + c] = out;
        jk[node * kC + c] = out;
    }
}

// ---- K2: xl = h@Wl + bl (fp16) ; xr = h@Wr + br (fp32).
// 256 threads: feature j x node-half; W columns in registers.
__global__ void __launch_bounds__(256) k_trans(
    const float* __restrict__ h,
    const float* __restrict__ Wl, const float* __restrict__ bl,
    const float* __restrict__ Wr, const float* __restrict__ br,
    __half* __restrict__ xl, float* __restrict__ xr) {
    __shared__ float s_h[32 * kC];
    int t = threadIdx.x;
    int j = t & 127, hf = t >> 7;
    float wl[kC], wr[kC];
    #pragma unroll
    for (int k = 0; k < kC; ++k) { wl[k] = Wl[k * kHC + j]; wr[k] = Wr[k * kHC + j]; }
    float blj = bl[j], brj = br[j];
    int n0 = blockIdx.x * 32;
    int nn = min(32, kNodes - n0);
    for (int i = t; i < nn * kC; i += 256) s_h[i] = h[n0 * kC + i];
    __syncthreads();
    int nend = min(nn, hf * 16 + 16);
    for (int n = hf * 16; n < nend; ++n) {
        const float4* h4 = (const float4*)(s_h + n * kC);
        float al = blj, ar = brj;
        #pragma unroll
        for (int kq = 0; kq < 8; ++kq) {
            float4 hv = h4[kq];
            al += hv.x * wl[kq*4] + hv.y * wl[kq*4+1] + hv.z * wl[kq*4+2] + hv.w * wl[kq*4+3];
            ar += hv.x * wr[kq*4] + hv.y * wr[kq*4+1] + hv.z * wr[kq*4+2] + hv.w * wr[kq*4+3];
        }
        long g = (long)(n0 + n) * kHC + j;
        xl[g] = __float2half(al);
        xr[g] = ar;
    }
}

// ---- CSR build (dst is layer-invariant: built ONCE)
__global__ void __launch_bounds__(256) k_hist(const int* __restrict__ dst, int* __restrict__ deg) {
    int e = blockIdx.x * 256 + threadIdx.x;
    if (e < kNE) atomicAdd(&deg[dst[e]], 1);
}

__global__ void __launch_bounds__(256) k_scan1(const int* __restrict__ deg,
                                               int* __restrict__ excl, int* __restrict__ bsum) {
    __shared__ int s[256];
    int t = threadIdx.x;
    int i = blockIdx.x * 256 + t;
    int v = (i < kNodes) ? deg[i] : 0;
    s[t] = v;
    __syncthreads();
    for (int o = 1; o < 256; o <<= 1) {
        int tv = (t >= o) ? s[t - o] : 0;
        __syncthreads();
        s[t] += tv;
        __syncthreads();
    }
    if (i < kNodes) excl[i] = s[t] - v;
    if (t == 255) bsum[blockIdx.x] = s[255];
}

__global__ void __launch_bounds__(256) k_scan2(int* __restrict__ bsum, int nb) {
    __shared__ int s[256];
    int t = threadIdx.x;
    int v = (t < nb) ? bsum[t] : 0;
    s[t] = v;
    __syncthreads();
    for (int o = 1; o < 256; o <<= 1) {
        int tv = (t >= o) ? s[t - o] : 0;
        __syncthreads();
        s[t] += tv;
        __syncthreads();
    }
    if (t < nb) bsum[t] = s[t];
}

__global__ void __launch_bounds__(256) k_scan3(int* __restrict__ excl, const int* __restrict__ bsum) {
    int i = blockIdx.x * 256 + threadIdx.x;
    if (i >= kNodes) return;
    if (blockIdx.x > 0) excl[i] += bsum[blockIdx.x - 1];
}

__global__ void __launch_bounds__(256) k_reorder(
    const int* __restrict__ src, const int* __restrict__ dst, const float* __restrict__ ea,
    const int* __restrict__ rowptr, int* __restrict__ cur,
    int* __restrict__ esrc, float* __restrict__ eea) {
    int e = blockIdx.x * 256 + threadIdx.x;
    if (e >= kNE) return;
    int d = dst[e];
    int pos = rowptr[d] + atomicAdd(&cur[d], 1);
    esrc[pos] = src[e];
    eea[pos]  = ea[e];
}

// ---- K3: fused edge phase, feature-parallel (r10/r12 layout).
__global__ void __launch_bounds__(128) k_edge(
    const int* __restrict__ rowptr, const int* __restrict__ deg,
    const int* __restrict__ esrc, const float* __restrict__ eea,
    const __half* __restrict__ xl, float* __restrict__ xrg,
    const float* __restrict__ We, const float* __restrict__ att,
    const float* __restrict__ gat_b, float* __restrict__ ps, float* __restrict__ pq) {
    __shared__ int   s_src[kCH];
    __shared__ float s_ea[kCH];
    __shared__ float s_red[4];
    int d = blockIdx.x;
    int j = threadIdx.x;                  // feature 0..127; head = j>>5
    long rowb = (long)d * kHC;
    float r_xr  = xrg[rowb + j];
    float r_We  = We[j];
    float r_att = att[j];
    float xlo   = __half2float(xl[rowb + j]);

    // self loop (ea = 0)
    float z = xlo + r_xr;
    z = (z > 0.f) ? z : kSlope * z;
    float p = z * r_att;
    #pragma unroll
    for (int mm = 1; mm < 32; mm <<= 1) p += __shfl_xor(p, mm);
    float ex = __expf(p - kShift);
    float l = ex, o = ex * xlo;

    int base = rowptr[d], cnt = deg[d];
    for (int eoff = 0; eoff < cnt; eoff += kCH) {
        int cc = min(kCH, cnt - eoff);
        __syncthreads();
        if (j < cc) { s_src[j] = esrc[base + eoff + j]; s_ea[j] = eea[base + eoff + j]; }
        __syncthreads();
        int e = 0;
        for (; e + 8 <= cc; e += 8) {
            float xv[8], pv[8];
            #pragma unroll
            for (int u = 0; u < 8; ++u)
                xv[u] = __half2float(xl[(long)s_src[e + u] * kHC + j]);
            #pragma unroll
            for (int u = 0; u < 8; ++u) {
                float zz = xv[u] + r_xr + s_ea[e + u] * r_We;
                zz = (zz > 0.f) ? zz : kSlope * zz;
                pv[u] = zz * r_att;
            }
            #pragma unroll
            for (int mm = 1; mm < 32; mm <<= 1) {
                #pragma unroll
                for (int u = 0; u < 8; ++u) pv[u] += __shfl_xor(pv[u], mm);
            }
            #pragma unroll
            for (int u = 0; u < 8; ++u) {
                float ee = __expf(pv[u] - kShift);
                l += ee;
                o += ee * xv[u];
            }
        }
        for (; e < cc; ++e) {
            float xe = __half2float(xl[(long)s_src[e] * kHC + j]);
            float ze = xe + r_xr + s_ea[e] * r_We;
            ze = (ze > 0.f) ? ze : kSlope * ze;
            float pe = ze * r_att;
            #pragma unroll
            for (int mm = 1; mm < 32; mm <<= 1) pe += __shfl_xor(pe, mm);
            float exe = __expf(pe - kShift);
            l += exe;
            o += exe * xe;
        }
    }
    float v = o / l;
    xrg[rowb + j] = v;                    // g overwrites xr (row-private)
    float vb = v + gat_b[j];
    float s = vb, q = vb * vb;
    #pragma unroll
    for (int off = 1; off < 64; off <<= 1) { s += __shfl_xor(s, off); q += __shfl_xor(q, off); }
    if ((j & 63) == 0) { s_red[(j >> 6) * 2] = s; s_red[(j >> 6) * 2 + 1] = q; }
    __syncthreads();
    if (j == 0) { ps[d] = s_red[0] + s_red[2]; pq[d] = s_red[1] + s_red[3]; }
}

// ---- K4: reduce per-node partials -> stats[2].
__global__ void __launch_bounds__(1024) k_statsr(
    const float* __restrict__ ps, const float* __restrict__ pq, float* __restrict__ stats) {
    __shared__ float rs[1024], rq[1024];
    int t = threadIdx.x;
    float s = 0.f, q = 0.f;
    for (int i = t; i < kNodes; i += 1024) { s += ps[i]; q += pq[i]; }
    rs[t] = s; rq[t] = q;
    __syncthreads();
    for (int o = 512; o > 0; o >>= 1) {
        if (t < o) { rs[t] += rs[t + o]; rq[t] += rq[t + o]; }
        __syncthreads();
    }
    if (t == 0) { stats[0] = rs[0]; stats[1] = rq[0]; }
}

// ---- K5: h = relu(node_ln(relu(graph_ln(g+gat_b)) @ lin_w + lin_b)); jk_out = max(jk_in, h)
__global__ void __launch_bounds__(256) k_post(
    const float* __restrict__ g, const float* __restrict__ gat_b,
    const float* __restrict__ ln1w, const float* __restrict__ ln1b,
    const float* __restrict__ linw, const float* __restrict__ linb,
    const float* __restrict__ ln2w, const float* __restrict__ ln2b,
    const float* __restrict__ stats, const float* __restrict__ jk_in,
    float* __restrict__ h, float* __restrict__ jk_out) {
    __shared__ float s_lw[kHC * kC];      // 16 KB
    __shared__ float s_vb[8 * kHC];       // 4 KB
    int t = threadIdx.x;
    int n0 = blockIdx.x * 8;
    const float inv = 1.f / ((float)kNodes * kHC);
    float mean = stats[0] * inv;
    float var  = stats[1] * inv - mean * mean;
    float rstd = rsqrtf(var + kEps);
    for (int i = t; i < kHC * kC; i += 256) s_lw[i] = linw[i];
    for (int i = t; i < 8 * kHC; i += 256) {
        int node = n0 + (i >> 7), f = i & 127;
        float a = (g[(long)node * kHC + f] + gat_b[f] - mean) * rstd * ln1w[f] + ln1b[f];
        s_vb[i] = fmaxf(a, 0.f);
    }
    __syncthreads();
    int n = t >> 5, c = t & 31;
    int node = n0 + n;
    float acc = linb[c];
    #pragma unroll 8
    for (int k = 0; k < kHC; ++k) acc += s_vb[n * kHC + k] * s_lw[k * kC + c];
    float m = acc;
    #pragma unroll
    for (int mm = 1; mm < 32; mm <<= 1) m += __shfl_xor(m, mm);
    m *= (1.f / kC);
    float dd = acc - m;
    float q = dd * dd;
    #pragma unroll
    for (int mm = 1; mm < 32; mm <<= 1) q += __shfl_xor(q, mm);
    q *= (1.f / kC);
    float out = dd * rsqrtf(q + kEps) * ln2w[c] + ln2b[c];
    out = fmaxf(out, 0.f);
    h[node * kC + c] = out;
    jk_out[node * kC + c] = fmaxf(jk_in[node * kC + c], out);
}

extern "C" void kernel_launch(void* const* d_in, const int* in_sizes, int n_in,
                              void* d_out, int out_size, void* d_ws, size_t ws_size,
                              hipStream_t stream) {
    (void)in_sizes; (void)n_in; (void)out_size; (void)ws_size;
    const float* x     = (const float*)d_in[0];
    const int*   ei    = (const int*)d_in[1];
    const int*   src   = ei;
    const int*   dst   = ei + kNE;
    const float* ea    = (const float*)d_in[2];
    const float* W_emb = (const float*)d_in[3];
    const float* b_emb = (const float*)d_in[4];
    const float* ln0w  = (const float*)d_in[5];
    const float* ln0b  = (const float*)d_in[6];
    const float* Wl    = (const float*)d_in[7];
    const float* bl    = (const float*)d_in[8];
    const float* Wr    = (const float*)d_in[9];
    const float* br    = (const float*)d_in[10];
    const float* We    = (const float*)d_in[11];
    const float* att   = (const float*)d_in[12];
    const float* gat_b = (const float*)d_in[13];
    const float* ln1w  = (const float*)d_in[14];
    const float* ln1b  = (const float*)d_in[15];
    const float* linw  = (const float*)d_in[16];
    const float* linb  = (const float*)d_in[17];
    const float* ln2w  = (const float*)d_in[18];
    const float* ln2b  = (const float*)d_in[19];

    char* wsb = (char*)d_ws;
    float*  h      = (float*)(wsb);                 // 6.4e6 B
    float*  jk     = (float*)(wsb +  6400000);      // 6.4e6 B
    float*  xrg    = (float*)(wsb + 12800000);      // 25.6e6 B (xr, later g)
    __half* xl     = (__half*)(wsb + 38400000);     // 12.8e6 B
    int*    esrc   = (int*)(wsb + 51200000);        // 3.2e6 B
    float*  eea    = (float*)(wsb + 54400000);      // 3.2e6 B
    int*    deg    = (int*)(wsb + 57600000);        // 0.2e6 B
    int*    cur    = (int*)(wsb + 57800000);        // 0.2e6 B
    int*    rowptr = (int*)(wsb + 58000000);        // 0.2e6 B
    int*    bsum   = (int*)(wsb + 58200000);        // 1 KB
    float*  stats  = (float*)(wsb + 58201024);      // 8 B
    float*  ps     = (float*)(wsb + 58300000);      // 0.2e6 B
    float*  pq     = (float*)(wsb + 58500000);      // 0.2e6 B

    const int scanBlocks  = (kNodes + 255) / 256;        // 196
    const int embedBlocks = kNodes / kTN;                // 3125 exact
    const int transBlocks = (kNodes + 31) / 32;          // 1563
    const int eBlocks     = (kNE + 255) / 256;
    const int postBlocks  = kNodes / 8;                  // 6250 exact

    hipLaunchKernelGGL(k_embed, dim3(embedBlocks), dim3(256), 0, stream,
                       x, W_emb, b_emb, ln0w, ln0b, h, jk);
    // CSR build (once; dst is layer-invariant)
    hipLaunchKernelGGL(k_fill0, dim3((2 * kNodes + 255) / 256), dim3(256), 0, stream,
                       (unsigned*)deg, 2 * kNodes);      // deg + cur
    hipLaunchKernelGGL(k_hist, dim3(eBlocks), dim3(256), 0, stream, dst, deg);
    hipLaunchKernelGGL(k_scan1, dim3(scanBlocks), dim3(256), 0, stream, deg, rowptr, bsum);
    hipLaunchKernelGGL(k_scan2, dim3(1), dim3(256), 0, stream, bsum, scanBlocks);
    hipLaunchKernelGGL(k_scan3, dim3(scanBlocks), dim3(256), 0, stream, rowptr, bsum);
    hipLaunchKernelGGL(k_reorder, dim3(eBlocks), dim3(256), 0, stream,
                       src, dst, ea, rowptr, cur, esrc, eea);
    for (int l = 0; l < 2; ++l) {
        hipLaunchKernelGGL(k_trans, dim3(transBlocks), dim3(256), 0, stream,
                           h, Wl + l * kC * kHC, bl + l * kHC,
                           Wr + l * kC * kHC, br + l * kHC, xl, xrg);
        hipLaunchKernelGGL(k_edge, dim3(kNodes), dim3(128), 0, stream,
                           rowptr, deg, esrc, eea, xl, xrg,
                           We + l * kHC, att + l * kH * kC, gat_b + l * kHC, ps, pq);
        hipLaunchKernelGGL(k_statsr, dim3(1), dim3(1024), 0, stream, ps, pq, stats);
        hipLaunchKernelGGL(k_post, dim3(postBlocks), dim3(256), 0, stream,
                           xrg, gat_b + l * kHC, ln1w + l * kHC, ln1b + l * kHC,
                           linw + l * kHC * kC, linb + l * kC,
                           ln2w + l * kC, ln2b + l * kC, stats, jk,
                           h, (l == 1) ? (float*)d_out : jk);
    }
}